// Round 3
// baseline (125.632 us; speedup 1.0000x reference)
//
#include <hip/hip_runtime.h>
#include <hip/hip_bf16.h>

// Reference collapses to: out[i, :] = tokens[i, :] * (probs[i,0] + probs[i,1]).
// The gather/argsort/scatter_add round-trip is the identity permutation:
//   unpermuted[s] = tokens[s // top_k] for every slot s.
// Indices input is unused. Pure memory-bound streaming scale.

#define N_TOKENS 16384
#define HIDDEN   4096

#define BLOCK   256
#define GRID    2048
#define NTHREADS (GRID * BLOCK)                    // 524288
#define TOTAL4  (N_TOKENS * (HIDDEN / 4))          // 16777216 float4
#define ITERS   (TOTAL4 / NTHREADS)                // exactly 32

typedef float f32x4 __attribute__((ext_vector_type(4)));
typedef float f32x2 __attribute__((ext_vector_type(2)));

// HIDDEN/4 = 1024 float4 per row -> row = float4_idx >> 10
__global__ __launch_bounds__(BLOCK) void moe_scale_kernel(
    const f32x4* __restrict__ tokens4,
    const f32x2* __restrict__ probs2,
    f32x4* __restrict__ out4)
{
    const int tid = blockIdx.x * BLOCK + threadIdx.x;
#pragma unroll 8
    for (int it = 0; it < ITERS; ++it) {
        const long long g = (long long)it * NTHREADS + tid;
        const int row = (int)(g >> 10);            // HIDDEN/4 == 1024
        const f32x2 p = probs2[row];               // one 8B load (L2-resident)
        const float scale = p.x + p.y;
        f32x4 t = __builtin_nontemporal_load(&tokens4[g]);
        t *= scale;
        __builtin_nontemporal_store(t, &out4[g]);
    }
}

extern "C" void kernel_launch(void* const* d_in, const int* in_sizes, int n_in,
                              void* d_out, int out_size, void* d_ws, size_t ws_size,
                              hipStream_t stream) {
    const f32x4* tokens4 = (const f32x4*)d_in[0];
    const f32x2* probs2  = (const f32x2*)d_in[1];
    // d_in[2] (indices) intentionally unused — see derivation above.
    f32x4* out4 = (f32x4*)d_out;

    moe_scale_kernel<<<GRID, BLOCK, 0, stream>>>(tokens4, probs2, out4);
}

// Round 4
// 105.145 us; speedup vs baseline: 1.1948x; 1.1948x over previous
//
#include <hip/hip_runtime.h>
#include <hip/hip_bf16.h>

// Reference collapses to: out[i, :] = tokens[i, :] * (probs[i,0] + probs[i,1]).
// The gather/argsort/scatter_add round-trip is the identity permutation:
//   unpermuted[s] = tokens[s // top_k] for every slot s.
// Indices input is unused. Pure memory-bound streaming scale.
//
// R3 lesson: __builtin_nontemporal_* regressed (125.6 vs 108.9 µs) — keep
// cached loads/stores. This round: block-contiguous 128 KiB regions,
// 32-bit indexing, 4-deep load batching for MLP.

#define N_TOKENS 16384
#define HIDDEN   4096

#define BLOCK    256
#define TOTAL4   (N_TOKENS * (HIDDEN / 4))   // 16777216 float4
#define GRID     2048
#define PER_BLK  (TOTAL4 / GRID)             // 8192 float4 = 8 rows = 128 KiB
#define NBATCH   4                           // loads in flight per thread
#define NITER    (PER_BLK / (BLOCK * NBATCH))// 8 outer iterations

typedef float f32x4 __attribute__((ext_vector_type(4)));
typedef float f32x2 __attribute__((ext_vector_type(2)));

__global__ __launch_bounds__(BLOCK) void moe_scale_kernel(
    const f32x4* __restrict__ tokens4,
    const f32x2* __restrict__ probs2,
    f32x4* __restrict__ out4)
{
    const int base = blockIdx.x * PER_BLK + threadIdx.x;   // fits in 32-bit
    for (int it = 0; it < NITER; ++it) {
        f32x4 v[NBATCH];
        float s[NBATCH];
#pragma unroll
        for (int u = 0; u < NBATCH; ++u) {
            const int g = base + (it * NBATCH + u) * BLOCK;
            v[u] = tokens4[g];                 // 4 dwordx4 loads back-to-back
            const int row = g >> 10;           // HIDDEN/4 == 1024
            const f32x2 p = probs2[row];       // wave-uniform, L2-resident
            s[u] = p.x + p.y;
        }
#pragma unroll
        for (int u = 0; u < NBATCH; ++u) {
            const int g = base + (it * NBATCH + u) * BLOCK;
            out4[g] = v[u] * s[u];
        }
    }
}

extern "C" void kernel_launch(void* const* d_in, const int* in_sizes, int n_in,
                              void* d_out, int out_size, void* d_ws, size_t ws_size,
                              hipStream_t stream) {
    const f32x4* tokens4 = (const f32x4*)d_in[0];
    const f32x2* probs2  = (const f32x2*)d_in[1];
    // d_in[2] (indices) intentionally unused — see derivation above.
    f32x4* out4 = (f32x4*)d_out;

    moe_scale_kernel<<<GRID, BLOCK, 0, stream>>>(tokens4, probs2, out4);
}

// Round 5
// 104.365 us; speedup vs baseline: 1.2038x; 1.0075x over previous
//
#include <hip/hip_runtime.h>
#include <hip/hip_bf16.h>

// Reference collapses to: out[i, :] = tokens[i, :] * (probs[i,0] + probs[i,1]).
// The gather/argsort/scatter_add round-trip is the identity permutation:
//   unpermuted[s] = tokens[s // top_k] for every slot s.
// Indices input is unused. Pure memory-bound streaming scale.
//
// R3 lesson: __builtin_nontemporal_* regressed (-20 us) — cached loads/stores.
// R4: block-contiguous 128 KiB regions + 4-deep batching -> 105.1 us.
// R5: 8-deep load batching + scale as wave-uniform scalar (row is a pure
//     function of blockIdx and the loop counter -> s_load, off the VMEM path).

#define N_TOKENS 16384
#define HIDDEN   4096

#define BLOCK    256
#define TOTAL4   (N_TOKENS * (HIDDEN / 4))    // 16777216 float4
#define GRID     2048
#define PER_BLK  (TOTAL4 / GRID)              // 8192 float4 = 8 rows = 128 KiB
#define NBATCH   8                            // loads in flight per thread
#define NITER    (PER_BLK / (BLOCK * NBATCH)) // 4 outer iterations, 2 rows each

typedef float f32x4 __attribute__((ext_vector_type(4)));
typedef float f32x2 __attribute__((ext_vector_type(2)));

__global__ __launch_bounds__(BLOCK) void moe_scale_kernel(
    const f32x4* __restrict__ tokens4,
    const f32x2* __restrict__ probs2,
    f32x4* __restrict__ out4)
{
    const int bid  = blockIdx.x;
    const int base = bid * PER_BLK + threadIdx.x;  // fits in 32-bit
    for (int it = 0; it < NITER; ++it) {
        f32x4 v[NBATCH];
#pragma unroll
        for (int u = 0; u < NBATCH; ++u)
            v[u] = tokens4[base + (it * NBATCH + u) * BLOCK]; // 8 dwordx4 in flight

        // Each iteration covers exactly 2 rows; row index is uniform
        // (function of blockIdx + it only) -> scalar loads.
        const int row0 = bid * (PER_BLK / (HIDDEN / 4)) + it * 2;
        const f32x2 p0 = probs2[row0];
        const f32x2 p1 = probs2[row0 + 1];
        const float s0 = p0.x + p0.y;
        const float s1 = p1.x + p1.y;

#pragma unroll
        for (int u = 0; u < NBATCH; ++u)
            out4[base + (it * NBATCH + u) * BLOCK] = v[u] * (u < NBATCH / 2 ? s0 : s1);
    }
}

extern "C" void kernel_launch(void* const* d_in, const int* in_sizes, int n_in,
                              void* d_out, int out_size, void* d_ws, size_t ws_size,
                              hipStream_t stream) {
    const f32x4* tokens4 = (const f32x4*)d_in[0];
    const f32x2* probs2  = (const f32x2*)d_in[1];
    // d_in[2] (indices) intentionally unused — see derivation above.
    f32x4* out4 = (f32x4*)d_out;

    moe_scale_kernel<<<GRID, BLOCK, 0, stream>>>(tokens4, probs2, out4);
}